// Round 9
// baseline (275.752 us; speedup 1.0000x reference)
//
#include <hip/hip_runtime.h>
#include <math.h>

#define N_NODES 100000
#define N_EDGES 1600000
#define IN_DIM  128
#define C1      64        // HEADS*HID layer-1 output channels
#define OUT_DIM 32
#define NEG_SLOPE 0.2f
#define LOG2E 1.44269504f

#define SLOTS   48                          // per-node capacity (max degree ~35 + self)
#define B1_BLOCKS ((N_EDGES + 2047) / 2048) // 782 binning blocks (8 edges/thread)
#define G1_BLOCKS ((N_NODES + 127) / 128)   // 782 gemm blocks (4 waves x 32 rows)

typedef _Float16 half8 __attribute__((ext_vector_type(8)));
typedef float    f32x4 __attribute__((ext_vector_type(4)));

// scores are pre-scaled by log2(e) at the producer (GEMM epilogue), so the
// softmax weight is exp2(lrelu(sc)) = v_mul + v_max + v_exp.
__device__ __forceinline__ float wexp2(float sc) {
    return __builtin_amdgcn_exp2f(fmaxf(sc, NEG_SLOPE * sc));
}

// ---------------- prep: weights fp16-transpose + deg zero (first dispatch) ---
// w1t[n][k]: n in [0,64), k in [0,128).  w2t[n][k]: n in [0,32), k in [0,64).
// Grid: 391 blocks so every deg entry gets one thread.
__global__ void prep_k(const float* __restrict__ W1, const float* __restrict__ W2,
                       _Float16* __restrict__ w1t, _Float16* __restrict__ w2t,
                       int* __restrict__ deg) {
    int t = blockIdx.x * 256 + threadIdx.x;
    if (t < N_NODES) deg[t] = 0;
    if (t < IN_DIM * C1) {
        int k = t >> 6, n = t & 63;
        w1t[n * IN_DIM + k] = (_Float16)W1[t];
    }
    if (t < C1 * OUT_DIM) {
        int k = t >> 5, n = t & 31;
        w2t[n * C1 + k] = (_Float16)W2[t];
    }
}

// ---------------- FUSED dispatch: direct CSR build | gemm1 -------------------
// Blocks 0..781: DIRECT atomic CSR build.  Per edge: one device atomicAdd on
// deg[dst] (returns slot; 8 independent atomics in flight per thread -- no
// serial chain) + one 4B scatter into csr[dst*48+slot].  This replaces the
// old two-phase buf/binp2 pipeline, which paid the scatter+atomic cost twice
// (round-8 counters showed scattered-write round trips, not occupancy, limit
// the binning pass).  Self-loop is injected later by the agg kernels.
// Blocks 782..1563: gemm1, round-7 geometry (4 waves x 32 rows, 18 KiB slab).
__global__ __launch_bounds__(256) void b1g1_k(const int* __restrict__ ei,
        int* __restrict__ deg, int* __restrict__ csr,
        const float* __restrict__ x, const _Float16* __restrict__ w1t,
        const float* __restrict__ a_s, const float* __restrict__ a_d,
        _Float16* __restrict__ h, float* __restrict__ as_o,
        float* __restrict__ ad_o) {
    __shared__ _Float16 sh[4][32 * 72];   // gemm1 slab (binning role: unused)
    int t = threadIdx.x;

    if (blockIdx.x < B1_BLOCKS) {
        // ============ direct CSR build: 2048 edges, 8 per thread ============
        #pragma unroll
        for (int i = 0; i < 8; ++i) {
            int e = blockIdx.x * 2048 + i * 256 + t;
            if (e < N_EDGES) {
                int s = ei[e];
                int d = ei[N_EDGES + e];
                int slot = atomicAdd(&deg[d], 1);
                if (slot < SLOTS) csr[d * SLOTS + slot] = s;
            }
        }
        return;
    }

    // ================= gemm1: h1 = x @ W1 + score dots =================
    int wv = t >> 6, lane = t & 63, m = lane & 15, q = lane >> 4;
    int rbw = (blockIdx.x - B1_BLOCKS) * 128 + wv * 32;
    f32x4 acc[2][4];
    #pragma unroll
    for (int i = 0; i < 2; ++i)
        #pragma unroll
        for (int j = 0; j < 4; ++j) acc[i][j] = (f32x4){0.f, 0.f, 0.f, 0.f};
    #pragma unroll
    for (int ks = 0; ks < 4; ++ks) {
        half8 a[2];
        #pragma unroll
        for (int rt = 0; rt < 2; ++rt) {
            int r = rbw + rt * 16 + m;
            r = r < N_NODES ? r : 0;
            const float4* p = (const float4*)(x + (size_t)r * IN_DIM + ks * 32 + q * 8);
            float4 f0 = p[0], f1 = p[1];
            half8 av;
            av[0] = (_Float16)f0.x; av[1] = (_Float16)f0.y;
            av[2] = (_Float16)f0.z; av[3] = (_Float16)f0.w;
            av[4] = (_Float16)f1.x; av[5] = (_Float16)f1.y;
            av[6] = (_Float16)f1.z; av[7] = (_Float16)f1.w;
            a[rt] = av;
        }
        #pragma unroll
        for (int ct = 0; ct < 4; ++ct) {
            half8 b = *(const half8*)(w1t + (ct * 16 + m) * IN_DIM + ks * 32 + q * 8);
            acc[0][ct] = __builtin_amdgcn_mfma_f32_16x16x32_f16(a[0], b, acc[0][ct], 0, 0, 0);
            acc[1][ct] = __builtin_amdgcn_mfma_f32_16x16x32_f16(a[1], b, acc[1][ct], 0, 0, 0);
        }
    }
    _Float16* ws = sh[wv];
    #pragma unroll
    for (int rt = 0; rt < 2; ++rt)
        #pragma unroll
        for (int ct = 0; ct < 4; ++ct)
            #pragma unroll
            for (int r = 0; r < 4; ++r)
                ws[(rt * 16 + q * 4 + r) * 72 + ct * 16 + m] = (_Float16)acc[rt][ct][r];
    __syncthreads();
    int rl = lane >> 1, hp = lane & 1;    // row-local 0..31, head = parity
    int rg = rbw + rl;
    if (rg < N_NODES) {
        float As_r[32], Ad_r[32];
        const float4* ap = (const float4*)(a_s + hp * 32);
        const float4* dp = (const float4*)(a_d + hp * 32);
        #pragma unroll
        for (int i = 0; i < 8; ++i) {
            float4 v = ap[i];
            As_r[4*i] = v.x; As_r[4*i+1] = v.y; As_r[4*i+2] = v.z; As_r[4*i+3] = v.w;
            float4 u = dp[i];
            Ad_r[4*i] = u.x; Ad_r[4*i+1] = u.y; Ad_r[4*i+2] = u.z; Ad_r[4*i+3] = u.w;
        }
        const _Float16* rowp = ws + rl * 72 + hp * 32;
        half8 c0 = *(const half8*)(rowp);
        half8 c1 = *(const half8*)(rowp + 8);
        half8 c2 = *(const half8*)(rowp + 16);
        half8 c3 = *(const half8*)(rowp + 24);
        float s = 0.f, dd = 0.f;
        #pragma unroll
        for (int j = 0; j < 8; ++j) {
            s  = fmaf((float)c0[j], As_r[j],      s);
            dd = fmaf((float)c0[j], Ad_r[j],      dd);
            s  = fmaf((float)c1[j], As_r[8 + j],  s);
            dd = fmaf((float)c1[j], Ad_r[8 + j],  dd);
            s  = fmaf((float)c2[j], As_r[16 + j], s);
            dd = fmaf((float)c2[j], Ad_r[16 + j], dd);
            s  = fmaf((float)c3[j], As_r[24 + j], s);
            dd = fmaf((float)c3[j], Ad_r[24 + j], dd);
        }
        as_o[rg * 2 + hp] = s  * LOG2E;
        ad_o[rg * 2 + hp] = dd * LOG2E;
        _Float16* hr = h + (size_t)rg * C1 + hp * 32;
        *(half8*)(hr)      = c0;
        *(half8*)(hr + 8)  = c1;
        *(half8*)(hr + 16) = c2;
        *(half8*)(hr + 24) = c3;
    }
}

// ---------------- FUSED: layer-1 aggregation + layer-2 GEMM ----------------
// Round-6/7 structure (best measured): LDS-staged CSR rows, 4 dst/wave,
// 2 eg x 8 cl, 8-edge flat batches; barrier; waves 1-3 exit; wave 0 runs
// gemm2 MFMA + score dots + h2 stores.  deg[] now holds the RAW edge count
// (self excluded); the self-loop is injected into the staged LDS rows here.
__global__ __launch_bounds__(256) void agg1g2_k(const int* __restrict__ deg,
        const int* __restrict__ csr, const _Float16* __restrict__ h1,
        const float* __restrict__ as1, const float* __restrict__ ad1,
        const float* __restrict__ b1, const _Float16* __restrict__ w2t,
        const float* __restrict__ a2s, const float* __restrict__ a2d,
        _Float16* __restrict__ h2, float* __restrict__ as2o,
        float* __restrict__ ad2o) {
    __shared__ int      srow[16 * SLOTS];   // staged rows (3 KiB)
    __shared__ _Float16 shu[16 * 72];       // helu tile, padded stride
    __shared__ _Float16 sh2[16 * 36];       // gemm2 C slab
    int t = threadIdx.x;
    int wv = t >> 6, lane = t & 63;
    int dl   = lane >> 4;          // dst-local 0..3
    int eg   = (lane >> 3) & 1;    // edge group 0..1
    int cl   = lane & 7;           // 8-half channel group
    int head = cl >> 2;
    int lr   = wv * 4 + dl;        // block-local row 0..15
    int d    = blockIdx.x * 16 + lr;

    // stage the 16 CSR rows (192 int4, coalesced), then inject self-loops
    if (t < 16 * SLOTS / 4)
        ((int4*)srow)[t] = ((const int4*)(csr + (size_t)blockIdx.x * 16 * SLOTS))[t];
    __syncthreads();
    if (t < 16) {
        int c = deg[blockIdx.x * 16 + t];
        int sl = c < SLOTS ? c : SLOTS - 1;
        srow[t * SLOTS + sl] = blockIdx.x * 16 + t;
    }
    __syncthreads();

    // ---- Phase A: layer-1 segment softmax + weighted sum ----
    int craw = deg[d];
    int cnt = (craw + 1) < SLOTS ? craw + 1 : SLOTS;
    const int* row = srow + lr * SLOTS;
    float advl = ad1[d * 2 + head];
    float acc[8] = {0.f, 0.f, 0.f, 0.f, 0.f, 0.f, 0.f, 0.f};
    float wsum = 0.f;
    for (int base = 0; base < cnt; base += 8) {
        int e0 = base + eg, e1 = e0 + 2, e2 = e0 + 4, e3 = e0 + 6;
        bool v0 = e0 < cnt, v1 = e1 < cnt, v2 = e2 < cnt, v3 = e3 < cnt;
        int s0 = row[v0 ? e0 : 0];
        int s1 = row[v1 ? e1 : 0];
        int s2 = row[v2 ? e2 : 0];
        int s3 = row[v3 ? e3 : 0];
        float a0 = as1[(unsigned)(s0 * 2 + head)];
        float a1 = as1[(unsigned)(s1 * 2 + head)];
        float a2 = as1[(unsigned)(s2 * 2 + head)];
        float a3 = as1[(unsigned)(s3 * 2 + head)];
        half8 g0 = *(const half8*)(h1 + (unsigned)(s0 * C1 + 8 * cl));
        half8 g1 = *(const half8*)(h1 + (unsigned)(s1 * C1 + 8 * cl));
        half8 g2 = *(const half8*)(h1 + (unsigned)(s2 * C1 + 8 * cl));
        half8 g3 = *(const half8*)(h1 + (unsigned)(s3 * C1 + 8 * cl));
        float w0 = v0 ? wexp2(a0 + advl) : 0.f;
        float w1 = v1 ? wexp2(a1 + advl) : 0.f;
        float w2 = v2 ? wexp2(a2 + advl) : 0.f;
        float w3 = v3 ? wexp2(a3 + advl) : 0.f;
        #pragma unroll
        for (int i = 0; i < 8; ++i) {
            acc[i] = fmaf((float)g0[i], w0, acc[i]);
            acc[i] = fmaf((float)g1[i], w1, acc[i]);
            acc[i] = fmaf((float)g2[i], w2, acc[i]);
            acc[i] = fmaf((float)g3[i], w3, acc[i]);
        }
        wsum += (w0 + w1) + (w2 + w3);
    }
    #pragma unroll
    for (int i = 0; i < 8; ++i) acc[i] += __shfl_xor(acc[i], 8);   // fold eg
    wsum += __shfl_xor(wsum, 8);
    if (eg == 0) {
        float inv = 1.f / (wsum + 1e-16f);
        const float4* bv = (const float4*)(b1 + 8 * cl);
        float o[8];
        #pragma unroll
        for (int i = 0; i < 4; ++i) {
            o[i]     = acc[i]     * inv + (&bv[0].x)[i];
            o[4 + i] = acc[4 + i] * inv + (&bv[1].x)[i];
        }
        half8 hv;
        #pragma unroll
        for (int i = 0; i < 8; ++i) {
            float e = o[i] > 0.f ? o[i] : __expf(o[i]) - 1.f;   // ELU
            hv[i] = (_Float16)e;
        }
        *(half8*)(shu + lr * 72 + cl * 8) = hv;
    }
    __syncthreads();
    if (wv != 0) return;           // waves 1-3 done: free the SIMD slots

    // ---- Phase B: gemm2 MFMA on the 16-row tile (wave 0 only) ----
    {
        int m = lane & 15, q = lane >> 4;
        f32x4 c2[2];
        c2[0] = (f32x4){0.f, 0.f, 0.f, 0.f};
        c2[1] = (f32x4){0.f, 0.f, 0.f, 0.f};
        #pragma unroll
        for (int ks = 0; ks < 2; ++ks) {
            half8 a = *(const half8*)(shu + m * 72 + ks * 32 + q * 8);
            #pragma unroll
            for (int ct = 0; ct < 2; ++ct) {
                half8 b = *(const half8*)(w2t + (ct * 16 + m) * C1 + ks * 32 + q * 8);
                c2[ct] = __builtin_amdgcn_mfma_f32_16x16x32_f16(a, b, c2[ct], 0, 0, 0);
            }
        }
        #pragma unroll
        for (int ct = 0; ct < 2; ++ct)
            #pragma unroll
            for (int r = 0; r < 4; ++r)
                sh2[(q * 4 + r) * 36 + ct * 16 + m] = (_Float16)c2[ct][r];
    }
    // same-wave cross-lane LDS dependence: drain LDS queue, no block barrier
    asm volatile("s_waitcnt lgkmcnt(0)" ::: "memory");
    __builtin_amdgcn_sched_barrier(0);

    // ---- Phase C: score dots + h2 write (wave 0, 16 rows x 4 parts) ----
    {
        int r = lane & 15, p = lane >> 4;
        int rg = blockIdx.x * 16 + r;
        const float4* ap = (const float4*)(a2s + p * 8);
        const float4* dp = (const float4*)(a2d + p * 8);
        float4 av0 = ap[0], av1 = ap[1];
        float4 dv0 = dp[0], dv1 = dp[1];
        float As[8] = {av0.x, av0.y, av0.z, av0.w, av1.x, av1.y, av1.z, av1.w};
        float Ad[8] = {dv0.x, dv0.y, dv0.z, dv0.w, dv1.x, dv1.y, dv1.z, dv1.w};
        half8 c = *(const half8*)(sh2 + r * 36 + p * 8);
        float s = 0.f, dd = 0.f;
        #pragma unroll
        for (int j = 0; j < 8; ++j) {
            s  = fmaf((float)c[j], As[j], s);
            dd = fmaf((float)c[j], Ad[j], dd);
        }
        s  += __shfl_xor(s, 16);  s  += __shfl_xor(s, 32);
        dd += __shfl_xor(dd, 16); dd += __shfl_xor(dd, 32);
        if (p == 0) {
            as2o[rg] = s  * LOG2E;
            ad2o[rg] = dd * LOG2E;
        }
        *(half8*)(h2 + (size_t)rg * OUT_DIM + p * 8) = c;
    }
}

// ---------------- Layer-2 aggregation ----------------
// 32 dsts/block (4 waves x 8); LDS-staged CSR rows + self-loop injection;
// 8 lanes per dst (2 eg x 4 cl spanning the 64B row); 8-edge flat batches.
__global__ __launch_bounds__(256) void agg2_k(const int* __restrict__ deg,
        const int* __restrict__ csr, const _Float16* __restrict__ h2,
        const float* __restrict__ as2, const float* __restrict__ ad2,
        const float* __restrict__ b2, float* __restrict__ out) {
    __shared__ int srow[32 * SLOTS];   // 6 KiB
    int t = threadIdx.x;
    int wv = t >> 6, lane = t & 63;
    int dl   = lane >> 3;          // dst-local 0..7
    int eg   = (lane >> 2) & 1;    // edge group 0..1
    int cl   = lane & 3;           // 8-half channel group
    int lr   = wv * 8 + dl;        // block-local row 0..31
    int d    = blockIdx.x * 32 + lr;

    // stage the 32 CSR rows (384 int4, coalesced), then inject self-loops
    {
        int4* s4 = (int4*)srow;
        const int4* g4 = (const int4*)(csr + (size_t)blockIdx.x * 32 * SLOTS);
        s4[t] = g4[t];
        if (t < 128) s4[256 + t] = g4[256 + t];
    }
    __syncthreads();
    if (t < 32) {
        int c = deg[blockIdx.x * 32 + t];
        int sl = c < SLOTS ? c : SLOTS - 1;
        srow[t * SLOTS + sl] = blockIdx.x * 32 + t;
    }
    __syncthreads();

    int craw = deg[d];
    int cnt = (craw + 1) < SLOTS ? craw + 1 : SLOTS;
    const int* row = srow + lr * SLOTS;
    float advl = ad2[d];
    float acc[8] = {0.f, 0.f, 0.f, 0.f, 0.f, 0.f, 0.f, 0.f};
    float wsum = 0.f;
    for (int base = 0; base < cnt; base += 8) {
        int e0 = base + eg, e1 = e0 + 2, e2 = e0 + 4, e3 = e0 + 6;
        bool v0 = e0 < cnt, v1 = e1 < cnt, v2 = e2 < cnt, v3 = e3 < cnt;
        int s0 = row[v0 ? e0 : 0];
        int s1 = row[v1 ? e1 : 0];
        int s2 = row[v2 ? e2 : 0];
        int s3 = row[v3 ? e3 : 0];
        float a0 = as2[(unsigned)s0];
        float a1 = as2[(unsigned)s1];
        float a2 = as2[(unsigned)s2];
        float a3 = as2[(unsigned)s3];
        half8 g0 = *(const half8*)(h2 + (unsigned)(s0 * OUT_DIM + 8 * cl));
        half8 g1 = *(const half8*)(h2 + (unsigned)(s1 * OUT_DIM + 8 * cl));
        half8 g2 = *(const half8*)(h2 + (unsigned)(s2 * OUT_DIM + 8 * cl));
        half8 g3 = *(const half8*)(h2 + (unsigned)(s3 * OUT_DIM + 8 * cl));
        float w0 = v0 ? wexp2(a0 + advl) : 0.f;
        float w1 = v1 ? wexp2(a1 + advl) : 0.f;
        float w2 = v2 ? wexp2(a2 + advl) : 0.f;
        float w3 = v3 ? wexp2(a3 + advl) : 0.f;
        #pragma unroll
        for (int i = 0; i < 8; ++i) {
            acc[i] = fmaf((float)g0[i], w0, acc[i]);
            acc[i] = fmaf((float)g1[i], w1, acc[i]);
            acc[i] = fmaf((float)g2[i], w2, acc[i]);
            acc[i] = fmaf((float)g3[i], w3, acc[i]);
        }
        wsum += (w0 + w1) + (w2 + w3);
    }
    #pragma unroll
    for (int i = 0; i < 8; ++i) acc[i] += __shfl_xor(acc[i], 4);   // fold eg
    wsum += __shfl_xor(wsum, 4);
    if (eg == 0) {
        float inv = 1.f / (wsum + 1e-16f);
        const float4* bv = (const float4*)(b2 + 8 * cl);
        float4 o0, o1;
        o0.x = acc[0] * inv + bv[0].x; o0.y = acc[1] * inv + bv[0].y;
        o0.z = acc[2] * inv + bv[0].z; o0.w = acc[3] * inv + bv[0].w;
        o1.x = acc[4] * inv + bv[1].x; o1.y = acc[5] * inv + bv[1].y;
        o1.z = acc[6] * inv + bv[1].z; o1.w = acc[7] * inv + bv[1].w;
        float4* ow = (float4*)(out + (size_t)d * OUT_DIM + 8 * cl);
        ow[0] = o0;
        ow[1] = o1;
    }
}

// ---------------- launch ----------------

extern "C" void kernel_launch(void* const* d_in, const int* in_sizes, int n_in,
                              void* d_out, int out_size, void* d_ws, size_t ws_size,
                              hipStream_t stream) {
    const float* x   = (const float*)d_in[0];
    const int*   ei  = (const int*)d_in[1];
    const float* W1  = (const float*)d_in[2];
    const float* a1s = (const float*)d_in[3];
    const float* a1d = (const float*)d_in[4];
    const float* b1  = (const float*)d_in[5];
    const float* W2  = (const float*)d_in[6];
    const float* a2s = (const float*)d_in[7];
    const float* a2d = (const float*)d_in[8];
    const float* b2  = (const float*)d_in[9];
    float* out = (float*)d_out;

    char* ws = (char*)d_ws;
    size_t off = 0;
    auto alloc = [&](size_t bytes) -> void* {
        void* p = ws + off;
        off = (off + bytes + 255) & ~(size_t)255;
        return p;
    };
    int* csr       = (int*)alloc((size_t)N_NODES * SLOTS * 4);          // 19.2 MB
    int* deg       = (int*)alloc((size_t)N_NODES * 4);                  // 0.4 MB
    _Float16* w1t  = (_Float16*)alloc((size_t)IN_DIM * C1 * 2);         // 16 KB
    _Float16* w2t  = (_Float16*)alloc((size_t)C1 * OUT_DIM * 2);        // 4 KB
    _Float16* h1   = (_Float16*)alloc((size_t)N_NODES * C1 * 2);        // 12.8 MB
    float* as1     = (float*)alloc((size_t)N_NODES * 2 * 4);
    float* ad1     = (float*)alloc((size_t)N_NODES * 2 * 4);
    _Float16* h2   = (_Float16*)alloc((size_t)N_NODES * OUT_DIM * 2);   // 6.4 MB
    float* as2     = (float*)alloc((size_t)N_NODES * 4);
    float* ad2     = (float*)alloc((size_t)N_NODES * 4);

    prep_k<<<(N_NODES + 255) / 256, 256, 0, stream>>>(W1, W2, w1t, w2t, deg);
    b1g1_k<<<B1_BLOCKS + G1_BLOCKS, 256, 0, stream>>>(ei, deg, csr,
                                                      x, w1t, a1s, a1d, h1, as1, ad1);
    agg1g2_k<<<N_NODES / 16, 256, 0, stream>>>(deg, csr, h1, as1, ad1, b1,
                                               w2t, a2s, a2d, h2, as2, ad2);
    agg2_k<<<N_NODES / 32, 256, 0, stream>>>(deg, csr, h2, as2, ad2, b2, out);
}

// Round 10
// 200.977 us; speedup vs baseline: 1.3721x; 1.3721x over previous
//
#include <hip/hip_runtime.h>
#include <math.h>

#define N_NODES 100000
#define N_EDGES 1600000
#define IN_DIM  128
#define C1      64        // HEADS*HID layer-1 output channels
#define OUT_DIM 32
#define NEG_SLOPE 0.2f
#define LOG2E 1.44269504f

#define BSHIFT  8
#define BNODES  256                         // nodes per bucket
#define NBUCK   ((N_NODES + BNODES - 1) / BNODES)   // 391
#define CAP     5120                        // bucket capacity (mean 4096, +16 sigma)
#define SLOTS   48                          // per-node capacity (max degree ~35 + self)
#define GC_STRIDE 16                        // bucket cursor: one per 64B line
#define G1_BLOCKS ((N_NODES + 127) / 128)   // 782 (128 rows/block, 32/wave)
#define B1_BLOCKS ((N_EDGES + 4095) / 4096) // 391 binning blocks

typedef _Float16 half8 __attribute__((ext_vector_type(8)));
typedef float    f32x4 __attribute__((ext_vector_type(4)));

// scores are pre-scaled by log2(e) at the producer (GEMM epilogue), so the
// softmax weight is exp2(lrelu(sc)) = v_mul + v_max + v_exp.
__device__ __forceinline__ float wexp2(float sc) {
    return __builtin_amdgcn_exp2f(fmaxf(sc, NEG_SLOPE * sc));
}

// ---------------- weight prep + gcur zero (first dispatch) ----------------
// w1t[n][k]: n in [0,64), k in [0,128).  w2t[n][k]: n in [0,32), k in [0,64).
__global__ void prep_k(const float* __restrict__ W1, const float* __restrict__ W2,
                       _Float16* __restrict__ w1t, _Float16* __restrict__ w2t,
                       int* __restrict__ gcur) {
    int t = blockIdx.x * 256 + threadIdx.x;
    if (t < NBUCK * GC_STRIDE) gcur[t] = 0;
    if (t < IN_DIM * C1) {
        int k = t >> 6, n = t & 63;
        w1t[n * IN_DIM + k] = (_Float16)W1[t];
    }
    if (t < C1 * OUT_DIM) {
        int k = t >> 5, n = t & 31;
        w2t[n * C1 + k] = (_Float16)W2[t];
    }
}

// ---------------- FUSED dispatch: binp1 (blocks 0..390) | gemm1 (rest) ------
// binp1 v2: LDS-COMPACTED write-out.  Round 7/8/9 established that the
// binning pass is limited by scattered-write transactions (write-coalescing
// quality maps monotonically to time: 10-edge runs/31MB/45us -> 5-edge/38MB/
// 57us -> 1-edge/111MB/130us).  Fix: place the block's 4096 edges into
// bucket-major order in LDS (histogram rank + 512-wide prefix sum), then
// stream out LDS-linear so consecutive lanes hit consecutive buf addresses
// within each bucket run (~8x fewer write transactions).  Global atomics and
// everything downstream (binp2, agg) identical to round 7.
__global__ __launch_bounds__(256) void b1g1_k(const int* __restrict__ ei,
        int* __restrict__ gcur, int* __restrict__ buf,
        const float* __restrict__ x, const _Float16* __restrict__ w1t,
        const float* __restrict__ a_s, const float* __restrict__ a_d,
        _Float16* __restrict__ h, float* __restrict__ as_o,
        float* __restrict__ ad_o) {
    __shared__ __align__(16) char smem[29312];   // max(binning 28.7K, gemm 18K)
    int t = threadIdx.x;

    if (blockIdx.x < B1_BLOCKS) {
        // ============ binp1: bin 4096 edges into bucket-major LDS ============
        int*            ledge = (int*)smem;                      // 4096 ints
        unsigned short* lbkt  = (unsigned short*)(smem + 16384); // 4096 u16
        int*            scnt  = (int*)(smem + 24576);            // 391
        int*            lbase = scnt + NBUCK;
        int*            sbase = lbase + NBUCK;
        for (int i = t; i < NBUCK; i += 256) scnt[i] = 0;
        __syncthreads();
        int pk[16], bk[16], p[16];
        bool v[16];
        #pragma unroll
        for (int i = 0; i < 16; ++i) {
            int e = blockIdx.x * 4096 + i * 256 + t;
            v[i] = e < N_EDGES;
            int ec = v[i] ? e : 0;
            int s = ei[ec];
            int d = ei[N_EDGES + ec];
            bk[i] = d >> BSHIFT;
            pk[i] = s | ((d & (BNODES - 1)) << 17);
            p[i] = v[i] ? atomicAdd(&scnt[bk[i]], 1) : 0;
        }
        __syncthreads();
        // inclusive scan of scnt (padded to 512); temps alias ledge
        int* sA = ledge;
        int* sB = ledge + 512;
        sA[t]       = t < NBUCK ? scnt[t] : 0;
        sA[t + 256] = (t + 256) < NBUCK ? scnt[t + 256] : 0;
        __syncthreads();
        int* pin = sA; int* pout = sB;
        for (int off = 1; off < 512; off <<= 1) {
            pout[t] = pin[t] + (t >= off ? pin[t - off] : 0);
            int k = t + 256;
            pout[k] = pin[k] + (k >= off ? pin[k - off] : 0);
            __syncthreads();
            int* tmp = pin; pin = pout; pout = tmp;
        }
        if (t < NBUCK) {
            lbase[t] = pin[t] - scnt[t];
            sbase[t] = scnt[t] ? atomicAdd(&gcur[t * GC_STRIDE], scnt[t]) : 0;
        }
        {
            int k = t + 256;
            if (k < NBUCK) {
                lbase[k] = pin[k] - scnt[k];
                sbase[k] = scnt[k] ? atomicAdd(&gcur[k * GC_STRIDE], scnt[k]) : 0;
            }
        }
        __syncthreads();
        #pragma unroll
        for (int i = 0; i < 16; ++i) {
            if (v[i]) {
                int slot = lbase[bk[i]] + p[i];
                ledge[slot] = pk[i];
                lbkt[slot] = (unsigned short)bk[i];
            }
        }
        __syncthreads();
        int Eb = N_EDGES - blockIdx.x * 4096;
        if (Eb > 4096) Eb = 4096;
        #pragma unroll
        for (int j = 0; j < 16; ++j) {
            int slot = j * 256 + t;
            if (slot < Eb) {
                int b = lbkt[slot];
                int pos = sbase[b] + (slot - lbase[b]);
                if (pos < CAP) buf[b * CAP + pos] = ledge[slot];
            }
        }
        return;
    }

    // ================= gemm1: h1 = x @ W1 + score dots =================
    _Float16 (*sh)[32 * 72] = (_Float16(*)[32 * 72])smem;
    int wv = t >> 6, lane = t & 63, m = lane & 15, q = lane >> 4;
    int rbw = (blockIdx.x - B1_BLOCKS) * 128 + wv * 32;
    f32x4 acc[2][4];
    #pragma unroll
    for (int i = 0; i < 2; ++i)
        #pragma unroll
        for (int j = 0; j < 4; ++j) acc[i][j] = (f32x4){0.f, 0.f, 0.f, 0.f};
    #pragma unroll
    for (int ks = 0; ks < 4; ++ks) {
        half8 a[2];
        #pragma unroll
        for (int rt = 0; rt < 2; ++rt) {
            int r = rbw + rt * 16 + m;
            r = r < N_NODES ? r : 0;
            const float4* p = (const float4*)(x + (size_t)r * IN_DIM + ks * 32 + q * 8);
            float4 f0 = p[0], f1 = p[1];
            half8 av;
            av[0] = (_Float16)f0.x; av[1] = (_Float16)f0.y;
            av[2] = (_Float16)f0.z; av[3] = (_Float16)f0.w;
            av[4] = (_Float16)f1.x; av[5] = (_Float16)f1.y;
            av[6] = (_Float16)f1.z; av[7] = (_Float16)f1.w;
            a[rt] = av;
        }
        #pragma unroll
        for (int ct = 0; ct < 4; ++ct) {
            half8 b = *(const half8*)(w1t + (ct * 16 + m) * IN_DIM + ks * 32 + q * 8);
            acc[0][ct] = __builtin_amdgcn_mfma_f32_16x16x32_f16(a[0], b, acc[0][ct], 0, 0, 0);
            acc[1][ct] = __builtin_amdgcn_mfma_f32_16x16x32_f16(a[1], b, acc[1][ct], 0, 0, 0);
        }
    }
    _Float16* ws = sh[wv];
    #pragma unroll
    for (int rt = 0; rt < 2; ++rt)
        #pragma unroll
        for (int ct = 0; ct < 4; ++ct)
            #pragma unroll
            for (int r = 0; r < 4; ++r)
                ws[(rt * 16 + q * 4 + r) * 72 + ct * 16 + m] = (_Float16)acc[rt][ct][r];
    __syncthreads();
    int rl = lane >> 1, hp = lane & 1;    // row-local 0..31, head = parity
    int rg = rbw + rl;
    if (rg < N_NODES) {
        float As_r[32], Ad_r[32];
        const float4* ap = (const float4*)(a_s + hp * 32);
        const float4* dp = (const float4*)(a_d + hp * 32);
        #pragma unroll
        for (int i = 0; i < 8; ++i) {
            float4 v = ap[i];
            As_r[4*i] = v.x; As_r[4*i+1] = v.y; As_r[4*i+2] = v.z; As_r[4*i+3] = v.w;
            float4 u = dp[i];
            Ad_r[4*i] = u.x; Ad_r[4*i+1] = u.y; Ad_r[4*i+2] = u.z; Ad_r[4*i+3] = u.w;
        }
        const _Float16* rowp = ws + rl * 72 + hp * 32;
        half8 c0 = *(const half8*)(rowp);
        half8 c1 = *(const half8*)(rowp + 8);
        half8 c2 = *(const half8*)(rowp + 16);
        half8 c3 = *(const half8*)(rowp + 24);
        float s = 0.f, dd = 0.f;
        #pragma unroll
        for (int j = 0; j < 8; ++j) {
            s  = fmaf((float)c0[j], As_r[j],      s);
            dd = fmaf((float)c0[j], Ad_r[j],      dd);
            s  = fmaf((float)c1[j], As_r[8 + j],  s);
            dd = fmaf((float)c1[j], Ad_r[8 + j],  dd);
            s  = fmaf((float)c2[j], As_r[16 + j], s);
            dd = fmaf((float)c2[j], Ad_r[16 + j], dd);
            s  = fmaf((float)c3[j], As_r[24 + j], s);
            dd = fmaf((float)c3[j], Ad_r[24 + j], dd);
        }
        as_o[rg * 2 + hp] = s  * LOG2E;
        ad_o[rg * 2 + hp] = dd * LOG2E;
        _Float16* hr = h + (size_t)rg * C1 + hp * 32;
        *(half8*)(hr)      = c0;
        *(half8*)(hr + 8)  = c1;
        *(half8*)(hr + 16) = c2;
        *(half8*)(hr + 24) = c3;
    }
}

// P2: one block per bucket. Place the bucket's edges into 256-node x 48-slot
// LDS rows via LDS atomics, append the SELF-LOOP (src = own node id) so the
// agg kernels need no special-case, then stream out as coalesced int4 + deg[].
__global__ __launch_bounds__(256) void binp2_k(const int* __restrict__ gcur,
        const int* __restrict__ buf, int* __restrict__ csr, int* __restrict__ deg) {
    __shared__ int4 lcsr4[BNODES * SLOTS / 4];   // 48 KiB
    __shared__ int  lcnt[BNODES];
    int* lcsr = (int*)lcsr4;
    int b = blockIdx.x, t = threadIdx.x;
    lcnt[t] = 0;
    __syncthreads();
    int cnt = gcur[b * GC_STRIDE];
    if (cnt > CAP) cnt = CAP;
    const int* bb = buf + b * CAP;
    for (int e = t; e < cnt; e += 256) {
        int vv = bb[e];
        int src = vv & 0x1FFFF;
        int l = vv >> 17;
        int slot = atomicAdd(&lcnt[l], 1);
        if (slot < SLOTS) lcsr[l * SLOTS + slot] = src;
    }
    __syncthreads();
    int c = lcnt[t];
    int slot = c < SLOTS ? c : SLOTS - 1;
    lcsr[t * SLOTS + slot] = b * BNODES + t;    // self loop
    int cd = c + 1;
    deg[b * BNODES + t] = cd < SLOTS ? cd : SLOTS;
    __syncthreads();
    int4* g4 = (int4*)csr + (size_t)b * (BNODES * SLOTS / 4);
    #pragma unroll
    for (int i = 0; i < BNODES * SLOTS / 4 / 256; ++i)   // 12 int4/thread
        g4[t + i * 256] = lcsr4[t + i * 256];
}

// ---------------- FUSED: layer-1 aggregation + layer-2 GEMM ----------------
// Round-6/7 structure (best measured): LDS-staged CSR rows, 4 dst/wave,
// 2 eg x 8 cl, 8-edge flat batches; barrier; waves 1-3 exit; wave 0 runs
// gemm2 MFMA + score dots + h2 stores.
__global__ __launch_bounds__(256) void agg1g2_k(const int* __restrict__ deg,
        const int* __restrict__ csr, const _Float16* __restrict__ h1,
        const float* __restrict__ as1, const float* __restrict__ ad1,
        const float* __restrict__ b1, const _Float16* __restrict__ w2t,
        const float* __restrict__ a2s, const float* __restrict__ a2d,
        _Float16* __restrict__ h2, float* __restrict__ as2o,
        float* __restrict__ ad2o) {
    __shared__ int      srow[16 * SLOTS];   // staged rows (3 KiB)
    __shared__ _Float16 shu[16 * 72];       // helu tile, padded stride
    __shared__ _Float16 sh2[16 * 36];       // gemm2 C slab
    int t = threadIdx.x;
    int wv = t >> 6, lane = t & 63;
    int dl   = lane >> 4;          // dst-local 0..3
    int eg   = (lane >> 3) & 1;    // edge group 0..1
    int cl   = lane & 7;           // 8-half channel group
    int head = cl >> 2;
    int lr   = wv * 4 + dl;        // block-local row 0..15
    int d    = blockIdx.x * 16 + lr;

    // stage the 16 CSR rows: 192 int4, coalesced
    if (t < 16 * SLOTS / 4)
        ((int4*)srow)[t] = ((const int4*)(csr + (size_t)blockIdx.x * 16 * SLOTS))[t];
    __syncthreads();

    // ---- Phase A: layer-1 segment softmax + weighted sum ----
    int cnt = deg[d];
    const int* row = srow + lr * SLOTS;
    float advl = ad1[d * 2 + head];
    float acc[8] = {0.f, 0.f, 0.f, 0.f, 0.f, 0.f, 0.f, 0.f};
    float wsum = 0.f;
    for (int base = 0; base < cnt; base += 8) {
        int e0 = base + eg, e1 = e0 + 2, e2 = e0 + 4, e3 = e0 + 6;
        bool v0 = e0 < cnt, v1 = e1 < cnt, v2 = e2 < cnt, v3 = e3 < cnt;
        int s0 = row[v0 ? e0 : 0];
        int s1 = row[v1 ? e1 : 0];
        int s2 = row[v2 ? e2 : 0];
        int s3 = row[v3 ? e3 : 0];
        float a0 = as1[(unsigned)(s0 * 2 + head)];
        float a1 = as1[(unsigned)(s1 * 2 + head)];
        float a2 = as1[(unsigned)(s2 * 2 + head)];
        float a3 = as1[(unsigned)(s3 * 2 + head)];
        half8 g0 = *(const half8*)(h1 + (unsigned)(s0 * C1 + 8 * cl));
        half8 g1 = *(const half8*)(h1 + (unsigned)(s1 * C1 + 8 * cl));
        half8 g2 = *(const half8*)(h1 + (unsigned)(s2 * C1 + 8 * cl));
        half8 g3 = *(const half8*)(h1 + (unsigned)(s3 * C1 + 8 * cl));
        float w0 = v0 ? wexp2(a0 + advl) : 0.f;
        float w1 = v1 ? wexp2(a1 + advl) : 0.f;
        float w2 = v2 ? wexp2(a2 + advl) : 0.f;
        float w3 = v3 ? wexp2(a3 + advl) : 0.f;
        #pragma unroll
        for (int i = 0; i < 8; ++i) {
            acc[i] = fmaf((float)g0[i], w0, acc[i]);
            acc[i] = fmaf((float)g1[i], w1, acc[i]);
            acc[i] = fmaf((float)g2[i], w2, acc[i]);
            acc[i] = fmaf((float)g3[i], w3, acc[i]);
        }
        wsum += (w0 + w1) + (w2 + w3);
    }
    #pragma unroll
    for (int i = 0; i < 8; ++i) acc[i] += __shfl_xor(acc[i], 8);   // fold eg
    wsum += __shfl_xor(wsum, 8);
    if (eg == 0) {
        float inv = 1.f / (wsum + 1e-16f);
        const float4* bv = (const float4*)(b1 + 8 * cl);
        float o[8];
        #pragma unroll
        for (int i = 0; i < 4; ++i) {
            o[i]     = acc[i]     * inv + (&bv[0].x)[i];
            o[4 + i] = acc[4 + i] * inv + (&bv[1].x)[i];
        }
        half8 hv;
        #pragma unroll
        for (int i = 0; i < 8; ++i) {
            float e = o[i] > 0.f ? o[i] : __expf(o[i]) - 1.f;   // ELU
            hv[i] = (_Float16)e;
        }
        *(half8*)(shu + lr * 72 + cl * 8) = hv;
    }
    __syncthreads();
    if (wv != 0) return;           // waves 1-3 done: free the SIMD slots

    // ---- Phase B: gemm2 MFMA on the 16-row tile (wave 0 only) ----
    {
        int m = lane & 15, q = lane >> 4;
        f32x4 c2[2];
        c2[0] = (f32x4){0.f, 0.f, 0.f, 0.f};
        c2[1] = (f32x4){0.f, 0.f, 0.f, 0.f};
        #pragma unroll
        for (int ks = 0; ks < 2; ++ks) {
            half8 a = *(const half8*)(shu + m * 72 + ks * 32 + q * 8);
            #pragma unroll
            for (int ct = 0; ct < 2; ++ct) {
                half8 b = *(const half8*)(w2t + (ct * 16 + m) * C1 + ks * 32 + q * 8);
                c2[ct] = __builtin_amdgcn_mfma_f32_16x16x32_f16(a, b, c2[ct], 0, 0, 0);
            }
        }
        #pragma unroll
        for (int ct = 0; ct < 2; ++ct)
            #pragma unroll
            for (int r = 0; r < 4; ++r)
                sh2[(q * 4 + r) * 36 + ct * 16 + m] = (_Float16)c2[ct][r];
    }
    // same-wave cross-lane LDS dependence: drain LDS queue, no block barrier
    asm volatile("s_waitcnt lgkmcnt(0)" ::: "memory");
    __builtin_amdgcn_sched_barrier(0);

    // ---- Phase C: score dots + h2 write (wave 0, 16 rows x 4 parts) ----
    {
        int r = lane & 15, p = lane >> 4;
        int rg = blockIdx.x * 16 + r;
        const float4* ap = (const float4*)(a2s + p * 8);
        const float4* dp = (const float4*)(a2d + p * 8);
        float4 av0 = ap[0], av1 = ap[1];
        float4 dv0 = dp[0], dv1 = dp[1];
        float As[8] = {av0.x, av0.y, av0.z, av0.w, av1.x, av1.y, av1.z, av1.w};
        float Ad[8] = {dv0.x, dv0.y, dv0.z, dv0.w, dv1.x, dv1.y, dv1.z, dv1.w};
        half8 c = *(const half8*)(sh2 + r * 36 + p * 8);
        float s = 0.f, dd = 0.f;
        #pragma unroll
        for (int j = 0; j < 8; ++j) {
            s  = fmaf((float)c[j], As[j], s);
            dd = fmaf((float)c[j], Ad[j], dd);
        }
        s  += __shfl_xor(s, 16);  s  += __shfl_xor(s, 32);
        dd += __shfl_xor(dd, 16); dd += __shfl_xor(dd, 32);
        if (p == 0) {
            as2o[rg] = s  * LOG2E;
            ad2o[rg] = dd * LOG2E;
        }
        *(half8*)(h2 + (size_t)rg * OUT_DIM + p * 8) = c;
    }
}

// ---------------- Layer-2 aggregation ----------------
// 32 dsts/block (4 waves x 8); LDS-staged CSR rows; 8 lanes per dst
// (2 eg x 4 cl spanning the 64B row); 8-edge flat batches; self-loop in CSR.
__global__ __launch_bounds__(256) void agg2_k(const int* __restrict__ deg,
        const int* __restrict__ csr, const _Float16* __restrict__ h2,
        const float* __restrict__ as2, const float* __restrict__ ad2,
        const float* __restrict__ b2, float* __restrict__ out) {
    __shared__ int srow[32 * SLOTS];   // 6 KiB
    int t = threadIdx.x;
    int wv = t >> 6, lane = t & 63;
    int dl   = lane >> 3;          // dst-local 0..7
    int eg   = (lane >> 2) & 1;    // edge group 0..1
    int cl   = lane & 3;           // 8-half channel group
    int lr   = wv * 8 + dl;        // block-local row 0..31
    int d    = blockIdx.x * 32 + lr;

    // stage the 32 CSR rows: 384 int4, coalesced
    {
        int4* s4 = (int4*)srow;
        const int4* g4 = (const int4*)(csr + (size_t)blockIdx.x * 32 * SLOTS);
        s4[t] = g4[t];
        if (t < 128) s4[256 + t] = g4[256 + t];
    }
    __syncthreads();

    int cnt = deg[d];
    const int* row = srow + lr * SLOTS;
    float advl = ad2[d];
    float acc[8] = {0.f, 0.f, 0.f, 0.f, 0.f, 0.f, 0.f, 0.f};
    float wsum = 0.f;
    for (int base = 0; base < cnt; base += 8) {
        int e0 = base + eg, e1 = e0 + 2, e2 = e0 + 4, e3 = e0 + 6;
        bool v0 = e0 < cnt, v1 = e1 < cnt, v2 = e2 < cnt, v3 = e3 < cnt;
        int s0 = row[v0 ? e0 : 0];
        int s1 = row[v1 ? e1 : 0];
        int s2 = row[v2 ? e2 : 0];
        int s3 = row[v3 ? e3 : 0];
        float a0 = as2[(unsigned)s0];
        float a1 = as2[(unsigned)s1];
        float a2 = as2[(unsigned)s2];
        float a3 = as2[(unsigned)s3];
        half8 g0 = *(const half8*)(h2 + (unsigned)(s0 * OUT_DIM + 8 * cl));
        half8 g1 = *(const half8*)(h2 + (unsigned)(s1 * OUT_DIM + 8 * cl));
        half8 g2 = *(const half8*)(h2 + (unsigned)(s2 * OUT_DIM + 8 * cl));
        half8 g3 = *(const half8*)(h2 + (unsigned)(s3 * OUT_DIM + 8 * cl));
        float w0 = v0 ? wexp2(a0 + advl) : 0.f;
        float w1 = v1 ? wexp2(a1 + advl) : 0.f;
        float w2 = v2 ? wexp2(a2 + advl) : 0.f;
        float w3 = v3 ? wexp2(a3 + advl) : 0.f;
        #pragma unroll
        for (int i = 0; i < 8; ++i) {
            acc[i] = fmaf((float)g0[i], w0, acc[i]);
            acc[i] = fmaf((float)g1[i], w1, acc[i]);
            acc[i] = fmaf((float)g2[i], w2, acc[i]);
            acc[i] = fmaf((float)g3[i], w3, acc[i]);
        }
        wsum += (w0 + w1) + (w2 + w3);
    }
    #pragma unroll
    for (int i = 0; i < 8; ++i) acc[i] += __shfl_xor(acc[i], 4);   // fold eg
    wsum += __shfl_xor(wsum, 4);
    if (eg == 0) {
        float inv = 1.f / (wsum + 1e-16f);
        const float4* bv = (const float4*)(b2 + 8 * cl);
        float4 o0, o1;
        o0.x = acc[0] * inv + bv[0].x; o0.y = acc[1] * inv + bv[0].y;
        o0.z = acc[2] * inv + bv[0].z; o0.w = acc[3] * inv + bv[0].w;
        o1.x = acc[4] * inv + bv[1].x; o1.y = acc[5] * inv + bv[1].y;
        o1.z = acc[6] * inv + bv[1].z; o1.w = acc[7] * inv + bv[1].w;
        float4* ow = (float4*)(out + (size_t)d * OUT_DIM + 8 * cl);
        ow[0] = o0;
        ow[1] = o1;
    }
}

// ---------------- launch ----------------

extern "C" void kernel_launch(void* const* d_in, const int* in_sizes, int n_in,
                              void* d_out, int out_size, void* d_ws, size_t ws_size,
                              hipStream_t stream) {
    const float* x   = (const float*)d_in[0];
    const int*   ei  = (const int*)d_in[1];
    const float* W1  = (const float*)d_in[2];
    const float* a1s = (const float*)d_in[3];
    const float* a1d = (const float*)d_in[4];
    const float* b1  = (const float*)d_in[5];
    const float* W2  = (const float*)d_in[6];
    const float* a2s = (const float*)d_in[7];
    const float* a2d = (const float*)d_in[8];
    const float* b2  = (const float*)d_in[9];
    float* out = (float*)d_out;

    char* ws = (char*)d_ws;
    size_t off = 0;
    auto alloc = [&](size_t bytes) -> void* {
        void* p = ws + off;
        off = (off + bytes + 255) & ~(size_t)255;
        return p;
    };
    int* gcur      = (int*)alloc((size_t)NBUCK * GC_STRIDE * 4);        // 25 KB
    int* buf       = (int*)alloc((size_t)NBUCK * CAP * 4);              // 8 MB
    int* csr       = (int*)alloc((size_t)NBUCK * BNODES * SLOTS * 4);   // 19.2 MB
    int* deg       = (int*)alloc((size_t)NBUCK * BNODES * 4);           // 0.4 MB
    _Float16* w1t  = (_Float16*)alloc((size_t)IN_DIM * C1 * 2);         // 16 KB
    _Float16* w2t  = (_Float16*)alloc((size_t)C1 * OUT_DIM * 2);        // 4 KB
    _Float16* h1   = (_Float16*)alloc((size_t)N_NODES * C1 * 2);        // 12.8 MB
    float* as1     = (float*)alloc((size_t)N_NODES * 2 * 4);
    float* ad1     = (float*)alloc((size_t)N_NODES * 2 * 4);
    _Float16* h2   = (_Float16*)alloc((size_t)N_NODES * OUT_DIM * 2);   // 6.4 MB
    float* as2     = (float*)alloc((size_t)N_NODES * 4);
    float* ad2     = (float*)alloc((size_t)N_NODES * 4);

    prep_k<<<(IN_DIM * C1 + 255) / 256, 256, 0, stream>>>(W1, W2, w1t, w2t, gcur);
    b1g1_k<<<B1_BLOCKS + G1_BLOCKS, 256, 0, stream>>>(ei, gcur, buf,
                                                      x, w1t, a1s, a1d, h1, as1, ad1);
    binp2_k<<<NBUCK, 256, 0, stream>>>(gcur, buf, csr, deg);
    agg1g2_k<<<N_NODES / 16, 256, 0, stream>>>(deg, csr, h1, as1, ad1, b1,
                                               w2t, a2s, a2d, h2, as2, ad2);
    agg2_k<<<N_NODES / 32, 256, 0, stream>>>(deg, csr, h2, as2, ad2, b2, out);
}